// Round 10
// baseline (371.587 us; speedup 1.0000x reference)
//
#include <hip/hip_runtime.h>
#include <hip/hip_bf16.h>
#include <math.h>

typedef __bf16 bf16;
typedef __bf16 bf16x2 __attribute__((ext_vector_type(2)));
typedef __bf16 bf16x4v __attribute__((ext_vector_type(4)));
typedef __bf16 bf16x8 __attribute__((ext_vector_type(8)));
typedef float  f32x4  __attribute__((ext_vector_type(4)));
typedef unsigned u32x4 __attribute__((ext_vector_type(4)));
typedef unsigned u32x2 __attribute__((ext_vector_type(2)));

#define HIDDEN 1024
#define TOKENS 4096   // B*S = 2*2048
#define FFDIM  4096
#define SEQ    2048
#define NHEAD  16

#define LOG2E 1.44269504088896340736f

// async 16B global -> LDS (lane i lands at ldsbase + 16*i)
__device__ __forceinline__ void async_copy16(bf16* lds, const bf16* g)
{
    __builtin_amdgcn_global_load_lds(
        (__attribute__((address_space(1))) void*)g,
        (__attribute__((address_space(3))) void*)lds,
        16, 0, 0);
}

// counted vmcnt wait (asm memory clobber doubles as compiler fence)
template<int N> __device__ __forceinline__ void waitv()
{
    if constexpr (N == 0)       asm volatile("s_waitcnt vmcnt(0)" ::: "memory");
    else if constexpr (N == 4)  asm volatile("s_waitcnt vmcnt(4)" ::: "memory");
    else if constexpr (N == 6)  asm volatile("s_waitcnt vmcnt(6)" ::: "memory");
    else if constexpr (N == 8)  asm volatile("s_waitcnt vmcnt(8)" ::: "memory");
    else if constexpr (N == 12) asm volatile("s_waitcnt vmcnt(12)" ::: "memory");
    else if constexpr (N == 16) asm volatile("s_waitcnt vmcnt(16)" ::: "memory");
}

__device__ __forceinline__ unsigned pack2(float lo, float hi)
{
    bf16x2 t; t[0] = (bf16)lo; t[1] = (bf16)hi;
    return __builtin_bit_cast(unsigned, t);
}

// v_permlane32_swap_b32 via builtin: returns {new_a, new_b}
__device__ __forceinline__ void pl32swap(unsigned& a, unsigned& b)
{
    u32x2 r = __builtin_amdgcn_permlane32_swap(a, b, false, false);
    a = r.x; b = r.y;
}

// GELU with A&S 7.1.26 erf approximation (|err| <= 1.5e-7)
__device__ __forceinline__ float gelu_fast(float v)
{
    float x = fabsf(v) * 0.70710678118654752f;
    float t = __builtin_amdgcn_rcpf(1.0f + 0.3275911f * x);
    float p = t * (0.254829592f + t * (-0.284496736f + t * (1.421413741f + t * (-1.453152027f + t * 1.061405429f))));
    float e = __builtin_amdgcn_exp2f(-x * x * LOG2E);
    float erfv = 1.0f - p * e;
    erfv = (v < 0.0f) ? -erfv : erfv;
    return 0.5f * v * (1.0f + erfv);
}

// ---------------- all weights fp32 -> bf16, one launch ----------------
__global__ __launch_bounds__(256) void cvt_all_kernel(const float* __restrict__ wq,
    const float* __restrict__ wk, const float* __restrict__ wv, const float* __restrict__ wo,
    const float* __restrict__ w1, const float* __restrict__ w2, bf16* __restrict__ out)
{
    size_t i = ((size_t)blockIdx.x * 256 + threadIdx.x) * 4;
    int sel = (int)(i >> 20);
    const float* src;
    size_t off;
    if (sel < 4) { src = (sel == 0) ? wq : (sel == 1) ? wk : (sel == 2) ? wv : wo; off = i & ((1u << 20) - 1); }
    else if (sel < 8) { src = w1; off = i - ((size_t)4 << 20); }
    else              { src = w2; off = i - ((size_t)8 << 20); }
    float4 v = *(const float4*)&src[off];
    bf16x4v o = { (bf16)v.x, (bf16)v.y, (bf16)v.z, (bf16)v.w };
    *(bf16x4v*)&out[i] = o;
}

__global__ __launch_bounds__(256) void concat_bias_kernel(const float* __restrict__ bq,
    const float* __restrict__ bk, const float* __restrict__ bv, float* __restrict__ o)
{
    int i = blockIdx.x * 256 + threadIdx.x;   // 0..3071
    float v = (i < 1024) ? bq[i] : (i < 2048 ? bk[i - 1024] : bv[i - 2048]);
    o[i] = v;
}

// ---------------- LayerNorm: fp32 in -> bf16 out, one block per row ----------------
__global__ __launch_bounds__(256) void ln_kernel(const float* __restrict__ in,
    const float* __restrict__ g, const float* __restrict__ be, bf16* __restrict__ out)
{
    int row = blockIdx.x;
    int tid = threadIdx.x;
    const float* x = in + (size_t)row * HIDDEN;
    int i0 = tid * 4;
    float4 v = *(const float4*)&x[i0];
    float s  = v.x + v.y + v.z + v.w;
    float s2 = v.x*v.x + v.y*v.y + v.z*v.z + v.w*v.w;
    #pragma unroll
    for (int off = 32; off > 0; off >>= 1) { s += __shfl_xor(s, off); s2 += __shfl_xor(s2, off); }
    __shared__ float red[2][4];
    int wave = tid >> 6;
    if ((tid & 63) == 0) { red[0][wave] = s; red[1][wave] = s2; }
    __syncthreads();
    float ts  = red[0][0] + red[0][1] + red[0][2] + red[0][3];
    float ts2 = red[1][0] + red[1][1] + red[1][2] + red[1][3];
    float mu   = ts  * (1.0f / HIDDEN);
    float var  = ts2 * (1.0f / HIDDEN) - mu * mu;
    float rstd = rsqrtf(var + 1e-5f);
    float4 gg = *(const float4*)&g[i0];
    float4 bb = *(const float4*)&be[i0];
    bf16x4v o;
    o[0] = (bf16)((v.x - mu) * rstd * gg.x + bb.x);
    o[1] = (bf16)((v.y - mu) * rstd * gg.y + bb.y);
    o[2] = (bf16)((v.z - mu) * rstd * gg.z + bb.z);
    o[3] = (bf16)((v.w - mu) * rstd * gg.w + bb.w);
    *(bf16x4v*)&out[(size_t)row * HIDDEN + i0] = o;
}

// ---------------- generic GEMM: C[M,N] = A[M,K] @ Bt[N,K]^T + bias ----------------
// Counted-vmcnt pipeline. NBUF=2: 1-deep prefetch; NBUF=3: 2-deep.
// EPI: 0 = bias, 1 = bias+GELU, 2 = bias+fp32 residual,
//      3 = split-K x2 over blockIdx.z: atomicAdd into fp32 C (bias on z==0).
// ROUND 10: EPI=3 + BM=64 + NBUF=2 (48KB LDS) -> grid 1024 blocks, 3 blocks/CU
// resident = 12 waves/CU. Tests the occupancy lever for FF2: all ~60us variants
// shared 8 waves/CU with no pipe saturated (dependency-chain limited).
template<int BM, int NBUF, int EPI, typename OT>
__global__ __launch_bounds__(256) void gemm_bt(const bf16* __restrict__ A, const bf16* __restrict__ Bt,
    const float* __restrict__ bias, const float* __restrict__ res, OT* __restrict__ C,
    int M, int N, int K)
{
    constexpr int MT = BM / 32;                 // m-tiles per wave
    constexpr int CP = BM / 32 + 4;             // staging copies per wave (6 or 8)
    __shared__ bf16 As[NBUF][BM * 64];
    __shared__ bf16 Bs[NBUF][128 * 64];
    int tid  = threadIdx.x;
    int wave = tid >> 6, lane = tid & 63;
    int lm = lane & 15, quad = lane >> 4;
    int m0 = blockIdx.x * BM, n0 = blockIdx.y * 128;
    int kspan = (EPI == 3) ? (K >> 1) : K;
    int kbase = (EPI == 3) ? blockIdx.z * kspan : 0;
    int wm = (wave >> 1) * (MT * 16), wn = (wave & 1) * 64;
    int r8 = lane >> 3, c8 = lane & 7;          // staging: 8 rows x 128B per copy
    int gsw = (c8 ^ (r8 & 7)) * 8;              // swizzled source column (elems)
    auto stage = [&](int buf, int k0) {
        #pragma unroll
        for (int ch = wave; ch < BM / 8; ch += 4)
            async_copy16(&As[buf][ch * 512], &A[(size_t)(m0 + ch * 8 + r8) * K + k0 + gsw]);
        #pragma unroll
        for (int ch = wave; ch < 16; ch += 4)
            async_copy16(&Bs[buf][ch * 512], &Bt[(size_t)(n0 + ch * 8 + r8) * K + k0 + gsw]);
    };
    f32x4 acc[MT][4] = {};
    int nk = kspan >> 6;
    stage(0, kbase);
    if (NBUF == 3) stage(1, kbase + 64);        // kspan >= 128 always
    for (int t = 0; t < nk; t++) {
        __builtin_amdgcn_sched_barrier(0);
        __builtin_amdgcn_s_barrier();           // A: readers of the buffer being restaged are done
        if (NBUF == 3) {
            if (t + 2 < nk) { stage((t + 2) % 3, kbase + (t + 2) * 64); waitv<2 * CP>(); }
            else if (t + 1 < nk) waitv<CP>();
            else waitv<0>();
        } else {
            if (t + 1 < nk) { stage((t + 1) & 1, kbase + (t + 1) * 64); waitv<CP>(); }
            else waitv<0>();
        }
        __builtin_amdgcn_sched_barrier(0);
        __builtin_amdgcn_s_barrier();           // B: stage(t) globally landed
        __builtin_amdgcn_sched_barrier(0);
        const bf16* as = As[(NBUF == 3) ? (t % 3) : (t & 1)];
        const bf16* bs = Bs[(NBUF == 3) ? (t % 3) : (t & 1)];
        bf16x8 af[MT][2], bfr[4][2];
        #pragma unroll
        for (int ks = 0; ks < 2; ks++) {
            int co = ((ks * 4 + quad) ^ (lm & 7)) * 8;
            #pragma unroll
            for (int t2 = 0; t2 < MT; t2++) af[t2][ks]  = *(const bf16x8*)&as[(wm + t2 * 16 + lm) * 64 + co];
            #pragma unroll
            for (int t2 = 0; t2 < 4; t2++)  bfr[t2][ks] = *(const bf16x8*)&bs[(wn + t2 * 16 + lm) * 64 + co];
        }
        #pragma unroll
        for (int mt = 0; mt < MT; mt++)
            #pragma unroll
            for (int nt = 0; nt < 4; nt++)
                #pragma unroll
                for (int ks = 0; ks < 2; ks++)
                    acc[mt][nt] = __builtin_amdgcn_mfma_f32_16x16x32_bf16(af[mt][ks], bfr[nt][ks], acc[mt][nt], 0, 0, 0);
    }
    bool addb = (EPI != 3) || (blockIdx.z == 0);
    #pragma unroll
    for (int mt = 0; mt < MT; mt++) {
        #pragma unroll
        for (int nt = 0; nt < 4; nt++) {
            int col = n0 + wn + nt * 16 + lm;
            float bv = addb ? bias[col] : 0.0f;
            #pragma unroll
            for (int r = 0; r < 4; r++) {
                int row = m0 + wm + mt * 16 + quad * 4 + r;
                float vv = acc[mt][nt][r] + bv;
                if (EPI == 1) vv = gelu_fast(vv);
                if (EPI == 2) vv += res[(size_t)row * N + col];
                if (EPI == 3) atomicAdd((float*)&C[(size_t)row * N + col], vv);
                else          C[(size_t)row * N + col] = (OT)vv;
            }
        }
    }
}

// ---------------- fused QKV GEMM: N=3072; V written transposed [b,h,d,s] ----------
// Counted-vmcnt pipeline (CP=8, double-buffer — 2 blocks/CU preserved).
__global__ __launch_bounds__(256) void gemm_qkv(const bf16* __restrict__ A, const bf16* __restrict__ W,
    const float* __restrict__ bias, bf16* __restrict__ qb, bf16* __restrict__ kb, bf16* __restrict__ vt)
{
    constexpr int K = HIDDEN;
    __shared__ bf16 As[2][128 * 64];
    __shared__ bf16 Bs[2][128 * 64];
    int tid  = threadIdx.x;
    int wave = tid >> 6, lane = tid & 63;
    int lm = lane & 15, quad = lane >> 4;
    int m0 = blockIdx.x * 128, n0 = blockIdx.y * 128;
    int wm = (wave >> 1) * 64, wn = (wave & 1) * 64;
    int r8 = lane >> 3, c8 = lane & 7;
    int gsw = (c8 ^ (r8 & 7)) * 8;
    auto stage = [&](int buf, int k0) {
        #pragma unroll
        for (int ch = wave; ch < 16; ch += 4) {
            async_copy16(&As[buf][ch * 512], &A[(size_t)(m0 + ch * 8 + r8) * K + k0 + gsw]);
            async_copy16(&Bs[buf][ch * 512], &W[(size_t)(n0 + ch * 8 + r8) * K + k0 + gsw]);
        }
    };
    f32x4 acc[4][4] = {};
    stage(0, 0);
    constexpr int nk = K >> 6;
    for (int t = 0; t < nk; t++) {
        __builtin_amdgcn_sched_barrier(0);
        __builtin_amdgcn_s_barrier();
        bool pre = (t + 1 < nk);
        if (pre) stage((t + 1) & 1, (t + 1) * 64);
        if (pre) waitv<8>(); else waitv<0>();
        __builtin_amdgcn_sched_barrier(0);
        __builtin_amdgcn_s_barrier();
        __builtin_amdgcn_sched_barrier(0);
        const bf16* as = As[t & 1];
        const bf16* bs = Bs[t & 1];
        bf16x8 af[4][2], bfr[4][2];
        #pragma unroll
        for (int ks = 0; ks < 2; ks++) {
            int co = ((ks * 4 + quad) ^ (lm & 7)) * 8;
            #pragma unroll
            for (int t2 = 0; t2 < 4; t2++) {
                af[t2][ks]  = *(const bf16x8*)&as[(wm + t2 * 16 + lm) * 64 + co];
                bfr[t2][ks] = *(const bf16x8*)&bs[(wn + t2 * 16 + lm) * 64 + co];
            }
        }
        #pragma unroll
        for (int mt = 0; mt < 4; mt++)
            #pragma unroll
            for (int nt = 0; nt < 4; nt++)
                #pragma unroll
                for (int ks = 0; ks < 2; ks++)
                    acc[mt][nt] = __builtin_amdgcn_mfma_f32_16x16x32_bf16(af[mt][ks], bfr[nt][ks], acc[mt][nt], 0, 0, 0);
    }
    int region = n0 >> 10;    // 0:Q 1:K 2:V  (block-uniform; 1024 % 128 == 0)
    #pragma unroll
    for (int mt = 0; mt < 4; mt++) {
        #pragma unroll
        for (int nt = 0; nt < 4; nt++) {
            int col = n0 + wn + nt * 16 + lm;
            float bv = bias[col];
            int cl = col & 1023;
            #pragma unroll
            for (int r = 0; r < 4; r++) {
                int row = m0 + wm + mt * 16 + quad * 4 + r;
                float vv = acc[mt][nt][r] + bv;
                if (region == 0)      qb[(size_t)row * HIDDEN + cl] = (bf16)vv;
                else if (region == 1) kb[(size_t)row * HIDDEN + cl] = (bf16)vv;
                else {
                    int h = cl >> 6, d = cl & 63;
                    int b = row >> 11, s = row & 2047;
                    vt[(((size_t)(b * NHEAD + h)) * 64 + d) * SEQ + s] = (bf16)vv;
                }
            }
        }
    }
}

// ---------------- Flash attention: 512 thr / 8 waves, wave-pair k-split ----------
// Round-8 state: counted-vmcnt CP=4, mask in LDS, setprio around MFMA clusters.
__global__ __launch_bounds__(512, 4) void attn_kernel(const bf16* __restrict__ Q, const bf16* __restrict__ K,
    const bf16* __restrict__ Vt, const float* __restrict__ mask, bf16* __restrict__ O)
{
    __shared__ bf16 smem[32768];                 // 65536 B: K 4 tiles + V 4 tiles
    __shared__ float maskLds[SEQ];               // 8 KB: mask row for this batch
    int tid = threadIdx.x, wave = tid >> 6, lane = tid & 63;
    int lm = lane & 15, quad = lane >> 4;
    int pair = wave >> 1, h = wave & 1;
    int bh = blockIdx.y, b = bh >> 4;
    int q0 = blockIdx.x * 128 + pair * 32;
    const size_t base  = ((size_t)b * SEQ) * HIDDEN + (bh & 15) * 64;  // Q/K token-major
    const size_t vbase = (size_t)bh * 64 * SEQ;                        // Vt [bh][d][s]
    int srow8 = lane >> 3, spos = lane & 7;
    // stage mask row (2048 floats, 512 threads x float4); visible after barrier A of gi=0
    ((float4*)maskLds)[tid] = ((const float4*)(mask + (size_t)b * SEQ))[tid];
    asm volatile("s_waitcnt lgkmcnt(0)" ::: "memory");
    bf16x8 qf[2][2];
    #pragma unroll
    for (int qt = 0; qt < 2; qt++)
        #pragma unroll
        for (int ks = 0; ks < 2; ks++)
            qf[qt][ks] = *(const bf16x8*)&Q[base + (size_t)(q0 + qt * 16 + lm) * HIDDEN + ks * 32 + quad * 8];
    bf16x8 onesf;
    #pragma unroll
    for (int i = 0; i < 8; i++) onesf[i] = (bf16)1.0f;
    f32x4 o[2][4] = {};
    f32x4 lacc[2] = {};                            // partial row-sums via MFMA vs ones
    const float c0 = 0.125f * LOG2E;               // score scale, log2 domain
    const float cmk = 10000.0f * LOG2E;            // mask scale, log2 domain
    const float coff = -(cmk + 16.0f);             // folds (mv-1)*cmk - SHIFT
    int r = wave * 8 + srow8;                      // this wave's staging row
    int gc = spos ^ (r & 7);                       // swizzled source chunk
    auto stage = [&](int gbuf, int ktg) {
        #pragma unroll
        for (int s = 0; s < 2; s++) {
            bf16* kd = smem + ((gbuf << 1) + s) * 4096;
            bf16* vd = smem + 16384 + ((gbuf << 1) + s) * 4096;
            int kt = ktg + s * 64;
            async_copy16(kd + wave * 512, &K [base  + (size_t)(kt + r) * HIDDEN + gc * 8]);
            async_copy16(vd + wave * 512, &Vt[vbase + (size_t)r * SEQ + kt + gc * 8]);
        }
    };
    stage(0, 0);
    int kh = h * 32;                               // this wave's k-half offset in tile
    bool qodd = (quad & 1);
    for (int gi = 0; gi < SEQ / 128; gi++) {
        __builtin_amdgcn_sched_barrier(0);
        __builtin_amdgcn_s_barrier();              // A: readers of buf^1 done (and mask staged, gi=0)
        bool pre = gi + 1 < SEQ / 128;
        if (pre) stage((gi + 1) & 1, (gi + 1) * 128);
        if (pre) waitv<4>(); else waitv<0>();      // own stage(gi) copies landed
        __builtin_amdgcn_sched_barrier(0);
        __builtin_amdgcn_s_barrier();              // B: stage(gi) globally landed
        __builtin_amdgcn_sched_barrier(0);
        #pragma unroll
        for (int sub = 0; sub < 2; sub++) {
            const bf16* ksb = smem + (((gi & 1) << 1) + sub) * 4096;
            const bf16* vsb = smem + 16384 + (((gi & 1) << 1) + sub) * 4096;
            int kt = gi * 128 + sub * 64;
            bf16x8 kf[2][2];
            #pragma unroll
            for (int nt = 0; nt < 2; nt++)
                #pragma unroll
                for (int ks = 0; ks < 2; ks++)
                    kf[nt][ks] = *(const bf16x8*)&ksb[(kh + nt * 16 + lm) * 64 + (((ks * 4 + quad) ^ (lm & 7)) * 8)];
            f32x4 st[2][2] = {};
            __builtin_amdgcn_s_setprio(1);
            #pragma unroll
            for (int qt = 0; qt < 2; qt++)
                #pragma unroll
                for (int nt = 0; nt < 2; nt++)
                    #pragma unroll
                    for (int ks = 0; ks < 2; ks++)
                        st[qt][nt] = __builtin_amdgcn_mfma_f32_16x16x32_bf16(kf[nt][ks], qf[qt][ks], st[qt][nt], 0, 0, 0);
            __builtin_amdgcn_s_setprio(0);
            float madd[2][4];
            #pragma unroll
            for (int nt = 0; nt < 2; nt++) {
                float4 mv = *(const float4*)&maskLds[kt + kh + nt * 16 + quad * 4];
                madd[nt][0] = mv.x * cmk + coff; madd[nt][1] = mv.y * cmk + coff;
                madd[nt][2] = mv.z * cmk + coff; madd[nt][3] = mv.w * cmk + coff;
            }
            bf16x8 af[2];
            #pragma unroll
            for (int qt = 0; qt < 2; qt++) {
                unsigned w[2][2];
                #pragma unroll
                for (int nt = 0; nt < 2; nt++) {
                    float p0 = __builtin_amdgcn_exp2f(st[qt][nt][0] * c0 + madd[nt][0]);
                    float p1 = __builtin_amdgcn_exp2f(st[qt][nt][1] * c0 + madd[nt][1]);
                    float p2 = __builtin_amdgcn_exp2f(st[qt][nt][2] * c0 + madd[nt][2]);
                    float p3 = __builtin_amdgcn_exp2f(st[qt][nt][3] * c0 + madd[nt][3]);
                    w[nt][0] = pack2(p0, p1);
                    w[nt][1] = pack2(p2, p3);
                }
                unsigned A0 = w[0][0], B0 = w[1][0];
                unsigned A1 = w[0][1], B1 = w[1][1];
                pl32swap(A0, B0);
                pl32swap(A1, B1);
                unsigned F0 = __shfl_xor(A0, 16), G0 = __shfl_xor(B0, 16);
                unsigned F1 = __shfl_xor(A1, 16), G1 = __shfl_xor(B1, 16);
                u32x4 uu;
                uu.x = qodd ? G0 : A0;
                uu.y = qodd ? G1 : A1;
                uu.z = qodd ? B0 : F0;
                uu.w = qodd ? B1 : F1;
                af[qt] = __builtin_bit_cast(bf16x8, uu);
                lacc[qt] = __builtin_amdgcn_mfma_f32_16x16x32_bf16(af[qt], onesf, lacc[qt], 0, 0, 0);
            }
            __builtin_amdgcn_s_setprio(1);
            #pragma unroll
            for (int dt = 0; dt < 4; dt++) {
                bf16x8 vf = *(const bf16x8*)&vsb[(dt * 16 + lm) * 64 + (((4 * h + quad) ^ (lm & 7)) * 8)];
                #pragma unroll
                for (int qt = 0; qt < 2; qt++)
                    o[qt][dt] = __builtin_amdgcn_mfma_f32_16x16x32_bf16(af[qt], vf, o[qt][dt], 0, 0, 0);
            }
            __builtin_amdgcn_s_setprio(0);
        }
    }
    // ---- pair combine (two passes, scratch overlays K/V buffers) ----
    __syncthreads();
    float* scratch = (float*)smem;
    float* s = scratch + ((size_t)pair * 64 + lane) * 20;
    if (h == 1) {
        #pragma unroll
        for (int dt = 0; dt < 4; dt++) *(f32x4*)&s[dt * 4] = o[0][dt];
        *(f32x4*)&s[16] = lacc[0];
    }
    __syncthreads();
    if (h == 0) {
        f32x4 pl = *(const f32x4*)&s[16];
        #pragma unroll
        for (int rr = 0; rr < 4; rr++) {
            float inv = 1.0f / (lacc[0][rr] + pl[rr]);
            #pragma unroll
            for (int dt = 0; dt < 4; dt++) {
                float val = (o[0][dt][rr] + s[dt * 4 + rr]) * inv;
                O[base + (size_t)(q0 + quad * 4 + rr) * HIDDEN + dt * 16 + lm] = (bf16)val;
            }
        }
    }
    __syncthreads();
    if (h == 0) {
        #pragma unroll
        for (int dt = 0; dt < 4; dt++) *(f32x4*)&s[dt * 4] = o[1][dt];
        *(f32x4*)&s[16] = lacc[1];
    }
    __syncthreads();
    if (h == 1) {
        f32x4 pl = *(const f32x4*)&s[16];
        #pragma unroll
        for (int rr = 0; rr < 4; rr++) {
            float inv = 1.0f / (lacc[1][rr] + pl[rr]);
            #pragma unroll
            for (int dt = 0; dt < 4; dt++) {
                float val = (o[1][dt][rr] + s[dt * 4 + rr]) * inv;
                O[base + (size_t)(q0 + 16 + quad * 4 + rr) * HIDDEN + dt * 16 + lm] = (bf16)val;
            }
        }
    }
}

extern "C" void kernel_launch(void* const* d_in, const int* in_sizes, int n_in,
                              void* d_out, int out_size, void* d_ws, size_t ws_size,
                              hipStream_t stream)
{
    (void)in_sizes; (void)n_in; (void)out_size; (void)ws_size;
    const float* x    = (const float*)d_in[0];
    const float* mask = (const float*)d_in[1];
    const float* Wq   = (const float*)d_in[2];
    const float* bq   = (const float*)d_in[3];
    const float* Wk   = (const float*)d_in[4];
    const float* bk   = (const float*)d_in[5];
    const float* Wv   = (const float*)d_in[6];
    const float* bv   = (const float*)d_in[7];
    const float* Wo   = (const float*)d_in[8];
    const float* bo   = (const float*)d_in[9];
    const float* W1   = (const float*)d_in[10];
    const float* b1   = (const float*)d_in[11];
    const float* W2   = (const float*)d_in[12];
    const float* b2   = (const float*)d_in[13];
    const float* g1   = (const float*)d_in[14];
    const float* be1  = (const float*)d_in[15];
    const float* g2   = (const float*)d_in[16];
    const float* be2  = (const float*)d_in[17];
    float* out = (float*)d_out;

    const size_t M1 = 1024u * 1024u;
    bf16* ws    = (bf16*)d_ws;
    bf16* Wqkv_b = ws;                  // 3M (Wq|Wk|Wv stacked = [3072][1024]), then Wo
    bf16* Wo_b  = ws + 3 * M1;          // 1M
    bf16* W1_b  = ws + 4 * M1;          // 4M
    bf16* W2_b  = ws + 8 * M1;          // 4M
    bf16* qb    = ws + 12 * M1;         // 4M
    bf16* kb    = ws + 16 * M1;         // 4M
    bf16* vt    = ws + 20 * M1;         // 4M  V transposed [b,h,d,s]
    bf16* cx    = ws + 24 * M1;         // 4M  attention context
    bf16* h     = ws + 28 * M1;         // 4M  LN output (h1, then h2)
    bf16* ffb   = ws + 12 * M1;         // 16M, overlays qb/kb/vt/cx (dead by FF1)
    float* biasqkv = (float*)(ws + 24 * M1);  // 3072 floats in cx region (dead before attn writes cx)

    cvt_all_kernel<<<dim3(12288), 256, 0, stream>>>(Wq, Wk, Wv, Wo, W1, W2, Wqkv_b);
    concat_bias_kernel<<<dim3(12), 256, 0, stream>>>(bq, bk, bv, biasqkv);

    ln_kernel<<<dim3(TOKENS), 256, 0, stream>>>(x, g1, be1, h);
    gemm_qkv<<<dim3(32, 24), 256, 0, stream>>>(h, Wqkv_b, biasqkv, qb, kb, vt);
    attn_kernel<<<dim3(SEQ / 128, 32), 512, 0, stream>>>(qb, kb, vt, mask, cx);
    gemm_bt<64, 3, 2, float><<<dim3(64, 8), 256, 0, stream>>>(cx, Wo_b, bo, x, out, TOKENS, HIDDEN, HIDDEN);
    ln_kernel<<<dim3(TOKENS), 256, 0, stream>>>(out, g2, be2, h);
    gemm_bt<128, 2, 1, bf16><<<dim3(32, 32), 256, 0, stream>>>(h, W1_b, b1, nullptr, ffb, TOKENS, FFDIM, HIDDEN);
    gemm_bt<64, 2, 3, float><<<dim3(64, 8, 2), 256, 0, stream>>>(ffb, W2_b, b2, nullptr, out, TOKENS, HIDDEN, FFDIM);
}

// Round 11
// 349.415 us; speedup vs baseline: 1.0635x; 1.0635x over previous
//
#include <hip/hip_runtime.h>
#include <hip/hip_bf16.h>
#include <math.h>

typedef __bf16 bf16;
typedef __bf16 bf16x2 __attribute__((ext_vector_type(2)));
typedef __bf16 bf16x4v __attribute__((ext_vector_type(4)));
typedef __bf16 bf16x8 __attribute__((ext_vector_type(8)));
typedef float  f32x4  __attribute__((ext_vector_type(4)));
typedef unsigned u32x4 __attribute__((ext_vector_type(4)));
typedef unsigned u32x2 __attribute__((ext_vector_type(2)));

#define HIDDEN 1024
#define TOKENS 4096   // B*S = 2*2048
#define FFDIM  4096
#define SEQ    2048
#define NHEAD  16

#define LOG2E 1.44269504088896340736f

// async 16B global -> LDS (lane i lands at ldsbase + 16*i)
__device__ __forceinline__ void async_copy16(bf16* lds, const bf16* g)
{
    __builtin_amdgcn_global_load_lds(
        (__attribute__((address_space(1))) void*)g,
        (__attribute__((address_space(3))) void*)lds,
        16, 0, 0);
}

// counted vmcnt wait (asm memory clobber doubles as compiler fence)
template<int N> __device__ __forceinline__ void waitv()
{
    if constexpr (N == 0)       asm volatile("s_waitcnt vmcnt(0)" ::: "memory");
    else if constexpr (N == 4)  asm volatile("s_waitcnt vmcnt(4)" ::: "memory");
    else if constexpr (N == 6)  asm volatile("s_waitcnt vmcnt(6)" ::: "memory");
    else if constexpr (N == 8)  asm volatile("s_waitcnt vmcnt(8)" ::: "memory");
    else if constexpr (N == 12) asm volatile("s_waitcnt vmcnt(12)" ::: "memory");
    else if constexpr (N == 16) asm volatile("s_waitcnt vmcnt(16)" ::: "memory");
}

__device__ __forceinline__ unsigned pack2(float lo, float hi)
{
    bf16x2 t; t[0] = (bf16)lo; t[1] = (bf16)hi;
    return __builtin_bit_cast(unsigned, t);
}

// v_permlane32_swap_b32 via builtin: returns {new_a, new_b}
__device__ __forceinline__ void pl32swap(unsigned& a, unsigned& b)
{
    u32x2 r = __builtin_amdgcn_permlane32_swap(a, b, false, false);
    a = r.x; b = r.y;
}

// GELU with A&S 7.1.26 erf approximation (|err| <= 1.5e-7)
__device__ __forceinline__ float gelu_fast(float v)
{
    float x = fabsf(v) * 0.70710678118654752f;
    float t = __builtin_amdgcn_rcpf(1.0f + 0.3275911f * x);
    float p = t * (0.254829592f + t * (-0.284496736f + t * (1.421413741f + t * (-1.453152027f + t * 1.061405429f))));
    float e = __builtin_amdgcn_exp2f(-x * x * LOG2E);
    float erfv = 1.0f - p * e;
    erfv = (v < 0.0f) ? -erfv : erfv;
    return 0.5f * v * (1.0f + erfv);
}

// ---------------- all weights fp32 -> bf16 + QKV bias concat, one launch ----------
// Blocks 0..12287: weight cvt (Wq|Wk|Wv|Wo|W1|W2 -> contiguous bf16).
// Blocks 12288..12299: concat bq|bk|bv -> fp32 biasqkv (saves one dispatch).
__global__ __launch_bounds__(256) void cvt_all_kernel(const float* __restrict__ wq,
    const float* __restrict__ wk, const float* __restrict__ wv, const float* __restrict__ wo,
    const float* __restrict__ w1, const float* __restrict__ w2, bf16* __restrict__ out,
    const float* __restrict__ bq, const float* __restrict__ bk, const float* __restrict__ bv,
    float* __restrict__ biasqkv)
{
    if (blockIdx.x >= 12288) {
        int i = (blockIdx.x - 12288) * 256 + threadIdx.x;   // 0..3071
        float v = (i < 1024) ? bq[i] : (i < 2048 ? bk[i - 1024] : bv[i - 2048]);
        biasqkv[i] = v;
        return;
    }
    size_t i = ((size_t)blockIdx.x * 256 + threadIdx.x) * 4;
    int sel = (int)(i >> 20);
    const float* src;
    size_t off;
    if (sel < 4) { src = (sel == 0) ? wq : (sel == 1) ? wk : (sel == 2) ? wv : wo; off = i & ((1u << 20) - 1); }
    else if (sel < 8) { src = w1; off = i - ((size_t)4 << 20); }
    else              { src = w2; off = i - ((size_t)8 << 20); }
    float4 v = *(const float4*)&src[off];
    bf16x4v o = { (bf16)v.x, (bf16)v.y, (bf16)v.z, (bf16)v.w };
    *(bf16x4v*)&out[i] = o;
}

// ---------------- LayerNorm: fp32 in -> bf16 out, one block per row ----------------
__global__ __launch_bounds__(256) void ln_kernel(const float* __restrict__ in,
    const float* __restrict__ g, const float* __restrict__ be, bf16* __restrict__ out)
{
    int row = blockIdx.x;
    int tid = threadIdx.x;
    const float* x = in + (size_t)row * HIDDEN;
    int i0 = tid * 4;
    float4 v = *(const float4*)&x[i0];
    float s  = v.x + v.y + v.z + v.w;
    float s2 = v.x*v.x + v.y*v.y + v.z*v.z + v.w*v.w;
    #pragma unroll
    for (int off = 32; off > 0; off >>= 1) { s += __shfl_xor(s, off); s2 += __shfl_xor(s2, off); }
    __shared__ float red[2][4];
    int wave = tid >> 6;
    if ((tid & 63) == 0) { red[0][wave] = s; red[1][wave] = s2; }
    __syncthreads();
    float ts  = red[0][0] + red[0][1] + red[0][2] + red[0][3];
    float ts2 = red[1][0] + red[1][1] + red[1][2] + red[1][3];
    float mu   = ts  * (1.0f / HIDDEN);
    float var  = ts2 * (1.0f / HIDDEN) - mu * mu;
    float rstd = rsqrtf(var + 1e-5f);
    float4 gg = *(const float4*)&g[i0];
    float4 bb = *(const float4*)&be[i0];
    bf16x4v o;
    o[0] = (bf16)((v.x - mu) * rstd * gg.x + bb.x);
    o[1] = (bf16)((v.y - mu) * rstd * gg.y + bb.y);
    o[2] = (bf16)((v.z - mu) * rstd * gg.z + bb.z);
    o[3] = (bf16)((v.w - mu) * rstd * gg.w + bb.w);
    *(bf16x4v*)&out[(size_t)row * HIDDEN + i0] = o;
}

// ---------------- generic GEMM: C[M,N] = A[M,K] @ Bt[N,K]^T + bias ----------------
// Counted-vmcnt pipeline (round-8 best config). NBUF=2: 1-deep prefetch;
// NBUF=3: 2-deep (BM=64 only: 72KB LDS keeps 2 blocks/CU).
// EPI: 0 = bias, 1 = bias+GELU, 2 = bias+fp32 residual.
template<int BM, int NBUF, int EPI, typename OT>
__global__ __launch_bounds__(256) void gemm_bt(const bf16* __restrict__ A, const bf16* __restrict__ Bt,
    const float* __restrict__ bias, const float* __restrict__ res, OT* __restrict__ C,
    int M, int N, int K)
{
    constexpr int MT = BM / 32;                 // m-tiles per wave
    constexpr int CP = BM / 32 + 4;             // staging copies per wave (6 or 8)
    __shared__ bf16 As[NBUF][BM * 64];
    __shared__ bf16 Bs[NBUF][128 * 64];
    int tid  = threadIdx.x;
    int wave = tid >> 6, lane = tid & 63;
    int lm = lane & 15, quad = lane >> 4;
    int m0 = blockIdx.x * BM, n0 = blockIdx.y * 128;
    int wm = (wave >> 1) * (MT * 16), wn = (wave & 1) * 64;
    int r8 = lane >> 3, c8 = lane & 7;          // staging: 8 rows x 128B per copy
    int gsw = (c8 ^ (r8 & 7)) * 8;              // swizzled source column (elems)
    auto stage = [&](int buf, int k0) {
        #pragma unroll
        for (int ch = wave; ch < BM / 8; ch += 4)
            async_copy16(&As[buf][ch * 512], &A[(size_t)(m0 + ch * 8 + r8) * K + k0 + gsw]);
        #pragma unroll
        for (int ch = wave; ch < 16; ch += 4)
            async_copy16(&Bs[buf][ch * 512], &Bt[(size_t)(n0 + ch * 8 + r8) * K + k0 + gsw]);
    };
    f32x4 acc[MT][4] = {};
    int nk = K >> 6;
    stage(0, 0);
    if (NBUF == 3) stage(1, 64);                // K >= 128 always
    for (int t = 0; t < nk; t++) {
        __builtin_amdgcn_sched_barrier(0);
        __builtin_amdgcn_s_barrier();           // A: readers of the buffer being restaged are done
        if (NBUF == 3) {
            if (t + 2 < nk) { stage((t + 2) % 3, (t + 2) * 64); waitv<2 * CP>(); }
            else if (t + 1 < nk) waitv<CP>();
            else waitv<0>();
        } else {
            if (t + 1 < nk) { stage((t + 1) & 1, (t + 1) * 64); waitv<CP>(); }
            else waitv<0>();
        }
        __builtin_amdgcn_sched_barrier(0);
        __builtin_amdgcn_s_barrier();           // B: stage(t) globally landed
        __builtin_amdgcn_sched_barrier(0);
        const bf16* as = As[(NBUF == 3) ? (t % 3) : (t & 1)];
        const bf16* bs = Bs[(NBUF == 3) ? (t % 3) : (t & 1)];
        bf16x8 af[MT][2], bfr[4][2];
        #pragma unroll
        for (int ks = 0; ks < 2; ks++) {
            int co = ((ks * 4 + quad) ^ (lm & 7)) * 8;
            #pragma unroll
            for (int t2 = 0; t2 < MT; t2++) af[t2][ks]  = *(const bf16x8*)&as[(wm + t2 * 16 + lm) * 64 + co];
            #pragma unroll
            for (int t2 = 0; t2 < 4; t2++)  bfr[t2][ks] = *(const bf16x8*)&bs[(wn + t2 * 16 + lm) * 64 + co];
        }
        #pragma unroll
        for (int mt = 0; mt < MT; mt++)
            #pragma unroll
            for (int nt = 0; nt < 4; nt++)
                #pragma unroll
                for (int ks = 0; ks < 2; ks++)
                    acc[mt][nt] = __builtin_amdgcn_mfma_f32_16x16x32_bf16(af[mt][ks], bfr[nt][ks], acc[mt][nt], 0, 0, 0);
    }
    #pragma unroll
    for (int mt = 0; mt < MT; mt++) {
        #pragma unroll
        for (int nt = 0; nt < 4; nt++) {
            int col = n0 + wn + nt * 16 + lm;
            float bv = bias[col];
            #pragma unroll
            for (int r = 0; r < 4; r++) {
                int row = m0 + wm + mt * 16 + quad * 4 + r;
                float vv = acc[mt][nt][r] + bv;
                if (EPI == 1) vv = gelu_fast(vv);
                if (EPI == 2) vv += res[(size_t)row * N + col];
                C[(size_t)row * N + col] = (OT)vv;
            }
        }
    }
}

// ---------------- fused QKV GEMM: N=3072; V written transposed [b,h,d,s] ----------
// Counted-vmcnt pipeline (CP=8, double-buffer — 2 blocks/CU preserved).
__global__ __launch_bounds__(256) void gemm_qkv(const bf16* __restrict__ A, const bf16* __restrict__ W,
    const float* __restrict__ bias, bf16* __restrict__ qb, bf16* __restrict__ kb, bf16* __restrict__ vt)
{
    constexpr int K = HIDDEN;
    __shared__ bf16 As[2][128 * 64];
    __shared__ bf16 Bs[2][128 * 64];
    int tid  = threadIdx.x;
    int wave = tid >> 6, lane = tid & 63;
    int lm = lane & 15, quad = lane >> 4;
    int m0 = blockIdx.x * 128, n0 = blockIdx.y * 128;
    int wm = (wave >> 1) * 64, wn = (wave & 1) * 64;
    int r8 = lane >> 3, c8 = lane & 7;
    int gsw = (c8 ^ (r8 & 7)) * 8;
    auto stage = [&](int buf, int k0) {
        #pragma unroll
        for (int ch = wave; ch < 16; ch += 4) {
            async_copy16(&As[buf][ch * 512], &A[(size_t)(m0 + ch * 8 + r8) * K + k0 + gsw]);
            async_copy16(&Bs[buf][ch * 512], &W[(size_t)(n0 + ch * 8 + r8) * K + k0 + gsw]);
        }
    };
    f32x4 acc[4][4] = {};
    stage(0, 0);
    constexpr int nk = K >> 6;
    for (int t = 0; t < nk; t++) {
        __builtin_amdgcn_sched_barrier(0);
        __builtin_amdgcn_s_barrier();
        bool pre = (t + 1 < nk);
        if (pre) stage((t + 1) & 1, (t + 1) * 64);
        if (pre) waitv<8>(); else waitv<0>();
        __builtin_amdgcn_sched_barrier(0);
        __builtin_amdgcn_s_barrier();
        __builtin_amdgcn_sched_barrier(0);
        const bf16* as = As[t & 1];
        const bf16* bs = Bs[t & 1];
        bf16x8 af[4][2], bfr[4][2];
        #pragma unroll
        for (int ks = 0; ks < 2; ks++) {
            int co = ((ks * 4 + quad) ^ (lm & 7)) * 8;
            #pragma unroll
            for (int t2 = 0; t2 < 4; t2++) {
                af[t2][ks]  = *(const bf16x8*)&as[(wm + t2 * 16 + lm) * 64 + co];
                bfr[t2][ks] = *(const bf16x8*)&bs[(wn + t2 * 16 + lm) * 64 + co];
            }
        }
        #pragma unroll
        for (int mt = 0; mt < 4; mt++)
            #pragma unroll
            for (int nt = 0; nt < 4; nt++)
                #pragma unroll
                for (int ks = 0; ks < 2; ks++)
                    acc[mt][nt] = __builtin_amdgcn_mfma_f32_16x16x32_bf16(af[mt][ks], bfr[nt][ks], acc[mt][nt], 0, 0, 0);
    }
    int region = n0 >> 10;    // 0:Q 1:K 2:V  (block-uniform; 1024 % 128 == 0)
    #pragma unroll
    for (int mt = 0; mt < 4; mt++) {
        #pragma unroll
        for (int nt = 0; nt < 4; nt++) {
            int col = n0 + wn + nt * 16 + lm;
            float bv = bias[col];
            int cl = col & 1023;
            #pragma unroll
            for (int r = 0; r < 4; r++) {
                int row = m0 + wm + mt * 16 + quad * 4 + r;
                float vv = acc[mt][nt][r] + bv;
                if (region == 0)      qb[(size_t)row * HIDDEN + cl] = (bf16)vv;
                else if (region == 1) kb[(size_t)row * HIDDEN + cl] = (bf16)vv;
                else {
                    int h = cl >> 6, d = cl & 63;
                    int b = row >> 11, s = row & 2047;
                    vt[(((size_t)(b * NHEAD + h)) * 64 + d) * SEQ + s] = (bf16)vv;
                }
            }
        }
    }
}

// ---------------- Flash attention: 512 thr / 8 waves, wave-pair k-split ----------
// Round-8 state: counted-vmcnt CP=4, mask in LDS, setprio around MFMA clusters.
__global__ __launch_bounds__(512, 4) void attn_kernel(const bf16* __restrict__ Q, const bf16* __restrict__ K,
    const bf16* __restrict__ Vt, const float* __restrict__ mask, bf16* __restrict__ O)
{
    __shared__ bf16 smem[32768];                 // 65536 B: K 4 tiles + V 4 tiles
    __shared__ float maskLds[SEQ];               // 8 KB: mask row for this batch
    int tid = threadIdx.x, wave = tid >> 6, lane = tid & 63;
    int lm = lane & 15, quad = lane >> 4;
    int pair = wave >> 1, h = wave & 1;
    int bh = blockIdx.y, b = bh >> 4;
    int q0 = blockIdx.x * 128 + pair * 32;
    const size_t base  = ((size_t)b * SEQ) * HIDDEN + (bh & 15) * 64;  // Q/K token-major
    const size_t vbase = (size_t)bh * 64 * SEQ;                        // Vt [bh][d][s]
    int srow8 = lane >> 3, spos = lane & 7;
    // stage mask row (2048 floats, 512 threads x float4); visible after barrier A of gi=0
    ((float4*)maskLds)[tid] = ((const float4*)(mask + (size_t)b * SEQ))[tid];
    asm volatile("s_waitcnt lgkmcnt(0)" ::: "memory");
    bf16x8 qf[2][2];
    #pragma unroll
    for (int qt = 0; qt < 2; qt++)
        #pragma unroll
        for (int ks = 0; ks < 2; ks++)
            qf[qt][ks] = *(const bf16x8*)&Q[base + (size_t)(q0 + qt * 16 + lm) * HIDDEN + ks * 32 + quad * 8];
    bf16x8 onesf;
    #pragma unroll
    for (int i = 0; i < 8; i++) onesf[i] = (bf16)1.0f;
    f32x4 o[2][4] = {};
    f32x4 lacc[2] = {};                            // partial row-sums via MFMA vs ones
    const float c0 = 0.125f * LOG2E;               // score scale, log2 domain
    const float cmk = 10000.0f * LOG2E;            // mask scale, log2 domain
    const float coff = -(cmk + 16.0f);             // folds (mv-1)*cmk - SHIFT
    int r = wave * 8 + srow8;                      // this wave's staging row
    int gc = spos ^ (r & 7);                       // swizzled source chunk
    auto stage = [&](int gbuf, int ktg) {
        #pragma unroll
        for (int s = 0; s < 2; s++) {
            bf16* kd = smem + ((gbuf << 1) + s) * 4096;
            bf16* vd = smem + 16384 + ((gbuf << 1) + s) * 4096;
            int kt = ktg + s * 64;
            async_copy16(kd + wave * 512, &K [base  + (size_t)(kt + r) * HIDDEN + gc * 8]);
            async_copy16(vd + wave * 512, &Vt[vbase + (size_t)r * SEQ + kt + gc * 8]);
        }
    };
    stage(0, 0);
    int kh = h * 32;                               // this wave's k-half offset in tile
    bool qodd = (quad & 1);
    for (int gi = 0; gi < SEQ / 128; gi++) {
        __builtin_amdgcn_sched_barrier(0);
        __builtin_amdgcn_s_barrier();              // A: readers of buf^1 done (and mask staged, gi=0)
        bool pre = gi + 1 < SEQ / 128;
        if (pre) stage((gi + 1) & 1, (gi + 1) * 128);
        if (pre) waitv<4>(); else waitv<0>();      // own stage(gi) copies landed
        __builtin_amdgcn_sched_barrier(0);
        __builtin_amdgcn_s_barrier();              // B: stage(gi) globally landed
        __builtin_amdgcn_sched_barrier(0);
        #pragma unroll
        for (int sub = 0; sub < 2; sub++) {
            const bf16* ksb = smem + (((gi & 1) << 1) + sub) * 4096;
            const bf16* vsb = smem + 16384 + (((gi & 1) << 1) + sub) * 4096;
            int kt = gi * 128 + sub * 64;
            bf16x8 kf[2][2];
            #pragma unroll
            for (int nt = 0; nt < 2; nt++)
                #pragma unroll
                for (int ks = 0; ks < 2; ks++)
                    kf[nt][ks] = *(const bf16x8*)&ksb[(kh + nt * 16 + lm) * 64 + (((ks * 4 + quad) ^ (lm & 7)) * 8)];
            f32x4 st[2][2] = {};
            __builtin_amdgcn_s_setprio(1);
            #pragma unroll
            for (int qt = 0; qt < 2; qt++)
                #pragma unroll
                for (int nt = 0; nt < 2; nt++)
                    #pragma unroll
                    for (int ks = 0; ks < 2; ks++)
                        st[qt][nt] = __builtin_amdgcn_mfma_f32_16x16x32_bf16(kf[nt][ks], qf[qt][ks], st[qt][nt], 0, 0, 0);
            __builtin_amdgcn_s_setprio(0);
            float madd[2][4];
            #pragma unroll
            for (int nt = 0; nt < 2; nt++) {
                float4 mv = *(const float4*)&maskLds[kt + kh + nt * 16 + quad * 4];
                madd[nt][0] = mv.x * cmk + coff; madd[nt][1] = mv.y * cmk + coff;
                madd[nt][2] = mv.z * cmk + coff; madd[nt][3] = mv.w * cmk + coff;
            }
            bf16x8 af[2];
            #pragma unroll
            for (int qt = 0; qt < 2; qt++) {
                unsigned w[2][2];
                #pragma unroll
                for (int nt = 0; nt < 2; nt++) {
                    float p0 = __builtin_amdgcn_exp2f(st[qt][nt][0] * c0 + madd[nt][0]);
                    float p1 = __builtin_amdgcn_exp2f(st[qt][nt][1] * c0 + madd[nt][1]);
                    float p2 = __builtin_amdgcn_exp2f(st[qt][nt][2] * c0 + madd[nt][2]);
                    float p3 = __builtin_amdgcn_exp2f(st[qt][nt][3] * c0 + madd[nt][3]);
                    w[nt][0] = pack2(p0, p1);
                    w[nt][1] = pack2(p2, p3);
                }
                unsigned A0 = w[0][0], B0 = w[1][0];
                unsigned A1 = w[0][1], B1 = w[1][1];
                pl32swap(A0, B0);
                pl32swap(A1, B1);
                unsigned F0 = __shfl_xor(A0, 16), G0 = __shfl_xor(B0, 16);
                unsigned F1 = __shfl_xor(A1, 16), G1 = __shfl_xor(B1, 16);
                u32x4 uu;
                uu.x = qodd ? G0 : A0;
                uu.y = qodd ? G1 : A1;
                uu.z = qodd ? B0 : F0;
                uu.w = qodd ? B1 : F1;
                af[qt] = __builtin_bit_cast(bf16x8, uu);
                lacc[qt] = __builtin_amdgcn_mfma_f32_16x16x32_bf16(af[qt], onesf, lacc[qt], 0, 0, 0);
            }
            __builtin_amdgcn_s_setprio(1);
            #pragma unroll
            for (int dt = 0; dt < 4; dt++) {
                bf16x8 vf = *(const bf16x8*)&vsb[(dt * 16 + lm) * 64 + (((4 * h + quad) ^ (lm & 7)) * 8)];
                #pragma unroll
                for (int qt = 0; qt < 2; qt++)
                    o[qt][dt] = __builtin_amdgcn_mfma_f32_16x16x32_bf16(af[qt], vf, o[qt][dt], 0, 0, 0);
            }
            __builtin_amdgcn_s_setprio(0);
        }
    }
    // ---- pair combine (two passes, scratch overlays K/V buffers) ----
    __syncthreads();
    float* scratch = (float*)smem;
    float* s = scratch + ((size_t)pair * 64 + lane) * 20;
    if (h == 1) {
        #pragma unroll
        for (int dt = 0; dt < 4; dt++) *(f32x4*)&s[dt * 4] = o[0][dt];
        *(f32x4*)&s[16] = lacc[0];
    }
    __syncthreads();
    if (h == 0) {
        f32x4 pl = *(const f32x4*)&s[16];
        #pragma unroll
        for (int rr = 0; rr < 4; rr++) {
            float inv = 1.0f / (lacc[0][rr] + pl[rr]);
            #pragma unroll
            for (int dt = 0; dt < 4; dt++) {
                float val = (o[0][dt][rr] + s[dt * 4 + rr]) * inv;
                O[base + (size_t)(q0 + quad * 4 + rr) * HIDDEN + dt * 16 + lm] = (bf16)val;
            }
        }
    }
    __syncthreads();
    if (h == 0) {
        #pragma unroll
        for (int dt = 0; dt < 4; dt++) *(f32x4*)&s[dt * 4] = o[1][dt];
        *(f32x4*)&s[16] = lacc[1];
    }
    __syncthreads();
    if (h == 1) {
        f32x4 pl = *(const f32x4*)&s[16];
        #pragma unroll
        for (int rr = 0; rr < 4; rr++) {
            float inv = 1.0f / (lacc[1][rr] + pl[rr]);
            #pragma unroll
            for (int dt = 0; dt < 4; dt++) {
                float val = (o[1][dt][rr] + s[dt * 4 + rr]) * inv;
                O[base + (size_t)(q0 + 16 + quad * 4 + rr) * HIDDEN + dt * 16 + lm] = (bf16)val;
            }
        }
    }
}

extern "C" void kernel_launch(void* const* d_in, const int* in_sizes, int n_in,
                              void* d_out, int out_size, void* d_ws, size_t ws_size,
                              hipStream_t stream)
{
    (void)in_sizes; (void)n_in; (void)out_size; (void)ws_size;
    const float* x    = (const float*)d_in[0];
    const float* mask = (const float*)d_in[1];
    const float* Wq   = (const float*)d_in[2];
    const float* bq   = (const float*)d_in[3];
    const float* Wk   = (const float*)d_in[4];
    const float* bk   = (const float*)d_in[5];
    const float* Wv   = (const float*)d_in[6];
    const float* bv   = (const float*)d_in[7];
    const float* Wo   = (const float*)d_in[8];
    const float* bo   = (const float*)d_in[9];
    const float* W1   = (const float*)d_in[10];
    const float* b1   = (const float*)d_in[11];
    const float* W2   = (const float*)d_in[12];
    const float* b2   = (const float*)d_in[13];
    const float* g1   = (const float*)d_in[14];
    const float* be1  = (const float*)d_in[15];
    const float* g2   = (const float*)d_in[16];
    const float* be2  = (const float*)d_in[17];
    float* out = (float*)d_out;

    const size_t M1 = 1024u * 1024u;
    bf16* ws    = (bf16*)d_ws;
    bf16* Wqkv_b = ws;                  // 3M (Wq|Wk|Wv stacked = [3072][1024]), then Wo
    bf16* Wo_b  = ws + 3 * M1;          // 1M
    bf16* W1_b  = ws + 4 * M1;          // 4M
    bf16* W2_b  = ws + 8 * M1;          // 4M
    bf16* qb    = ws + 12 * M1;         // 4M
    bf16* kb    = ws + 16 * M1;         // 4M
    bf16* vt    = ws + 20 * M1;         // 4M  V transposed [b,h,d,s]
    bf16* cx    = ws + 24 * M1;         // 4M  attention context
    bf16* h     = ws + 28 * M1;         // 4M  LN output (h1, then h2)
    bf16* ffb   = ws + 12 * M1;         // 16M, overlays qb/kb/vt/cx (dead by FF1)
    float* biasqkv = (float*)(ws + 24 * M1);  // 3072 floats in cx region (dead before attn writes cx)

    cvt_all_kernel<<<dim3(12300), 256, 0, stream>>>(Wq, Wk, Wv, Wo, W1, W2, Wqkv_b,
                                                    bq, bk, bv, biasqkv);

    ln_kernel<<<dim3(TOKENS), 256, 0, stream>>>(x, g1, be1, h);
    gemm_qkv<<<dim3(32, 24), 256, 0, stream>>>(h, Wqkv_b, biasqkv, qb, kb, vt);
    attn_kernel<<<dim3(SEQ / 128, 32), 512, 0, stream>>>(qb, kb, vt, mask, cx);
    gemm_bt<64, 3, 2, float><<<dim3(64, 8), 256, 0, stream>>>(cx, Wo_b, bo, x, out, TOKENS, HIDDEN, HIDDEN);
    ln_kernel<<<dim3(TOKENS), 256, 0, stream>>>(out, g2, be2, h);
    gemm_bt<128, 2, 1, bf16><<<dim3(32, 32), 256, 0, stream>>>(h, W1_b, b1, nullptr, ffb, TOKENS, FFDIM, HIDDEN);
    gemm_bt<64, 3, 2, float><<<dim3(64, 8), 256, 0, stream>>>(ffb, W2_b, b2, out, out, TOKENS, HIDDEN, FFDIM);
}